// Round 7
// baseline (4543.465 us; speedup 1.0000x reference)
//
#include <hip/hip_runtime.h>

#define HDIM 2048
#define TSTEPS 1024
#define NBLK 256
#define NTHR 512
#define CPB 8      // columns per block

typedef unsigned long long ull;

__device__ __forceinline__ int snake_src(int t) {
    int y = t >> 5, p = t & 31;
    return (y & 1) ? (y * 32 + 31 - p) : t;
}
__device__ __forceinline__ float sigmoid_f(float v) {
    return __builtin_amdgcn_rcpf(1.f + __expf(-v));
}
__device__ __forceinline__ float tanh_f(float v) {
    return 1.f - 2.f * __builtin_amdgcn_rcpf(__expf(2.f * v) + 1.f);
}
__device__ __forceinline__ int P(int i) { return i + (i >> 5); }  // stride-33 pad

// ---------------------------------------------------------------------------
// Persistent kernel. 256 blocks x 512 threads; block owns 8 columns.
// Wave wv (0..7) owns column col = blk*8+wv; lane l owns rows [32l, 32l+32).
// 96 recurrent-weight floats per thread stay register-resident.
//
// Sync redesign vs R3-R6: per-block FLAG + contiguous PAYLOAD instead of
// 2048 tagged slots. Release: lane0 of each wave stores h[col] (4B agent
// atomic), __syncthreads (drains vmcnt(0) per wave BEFORE s_barrier =>
// all 8 payload stores ACKed at coherence point), tid0 stores flags[blk]=t+1.
// Discovery: poller thread b (tid<256) spins on flags[b] >= t ONLY (1 flag
// per thread, 16 lines/block/round = 16x less poll traffic than slot scheme),
// then immediately fetches producer b's 32B payload (4x 8B agent loads) and
// stages it to LDS. Straggler wait overlaps payload fetch. One barrier
// releases compute. LDS h double-buffered; stride-33 => conflict-free reads.
// Flags are monotonic ints; 0xAA poison = negative => never >= t.
// 2-buffer payload safety: block publishes t+1 only after consuming t, which
// implies every block published t, which implies every block consumed t-1.
// ---------------------------------------------------------------------------
__global__ __launch_bounds__(NTHR, 1) void gru_all(
    const float* __restrict__ x,
    const float* __restrict__ We,  const float* __restrict__ be,
    const float* __restrict__ Wir, const float* __restrict__ bir,
    const float* __restrict__ Wiz, const float* __restrict__ biz,
    const float* __restrict__ Win, const float* __restrict__ bin_,
    const float* __restrict__ Whr, const float* __restrict__ Whz,
    const float* __restrict__ Whn, const float* __restrict__ bhn,
    float* __restrict__ out, int* __restrict__ flags, float* __restrict__ dbuf)
{
    const int tid  = threadIdx.x;
    const int blk  = blockIdx.x;
    const int lane = tid & 63;
    const int wv   = tid >> 6;            // 0..7
    const int col  = blk * CPB + wv;
    const int row0 = lane * 32;

    __shared__ float lds_h[2][2112];      // stride-33 padded h (double buffer)
    __shared__ float xs_l[TSTEPS];

    // ---- stage snake-ordered x ----
    for (int i = tid; i < TSTEPS; i += NTHR) xs_l[i] = x[snake_src(i)];

    // ---- recurrent weights into registers (one-time, stays resident) ----
    float wr[32], wz[32], wn[32];
#pragma unroll
    for (int k = 0; k < 32; ++k) {
        size_t off = (size_t)(row0 + k) * HDIM + col;
        wr[k] = Whr[off];
        wz[k] = Whz[off];
        wn[k] = Whn[off];
    }

    // ---- rank-1 input-path constants for this wave's column ----
    float vrc = 0, vzc = 0, vnc = 0, crc = 0, czc = 0, cnc = 0;
#pragma unroll 8
    for (int k = 0; k < 32; ++k) {
        size_t off = (size_t)(row0 + k) * HDIM + col;
        float we = We[row0 + k], bb = be[row0 + k];
        float w0 = Wir[off], w1 = Wiz[off], w2 = Win[off];
        vrc = fmaf(we, w0, vrc);  crc = fmaf(bb, w0, crc);
        vzc = fmaf(we, w1, vzc);  czc = fmaf(bb, w1, czc);
        vnc = fmaf(we, w2, vnc);  cnc = fmaf(bb, w2, cnc);
    }
#pragma unroll
    for (int m = 1; m < 64; m <<= 1) {
        vrc += __shfl_xor(vrc, m, 64); vzc += __shfl_xor(vzc, m, 64);
        vnc += __shfl_xor(vnc, m, 64); crc += __shfl_xor(crc, m, 64);
        czc += __shfl_xor(czc, m, 64); cnc += __shfl_xor(cnc, m, 64);
    }
    crc += bir[col]; czc += biz[col]; cnc += bin_[col];
    const float bhc = bhn[col];

    __syncthreads();   // xs_l ready

    // ---- step 0: h_0 == 0, fully local; publish h_1 ----
    float h_prev;
    {
        float x0 = xs_l[0];
        float ar = fmaf(x0, vrc, crc);
        float az = fmaf(x0, vzc, czc);
        float an = fmaf(x0, vnc, cnc);
        float rg = sigmoid_f(ar), zg = sigmoid_f(az);
        float ng = tanh_f(fmaf(rg, bhc, an));
        h_prev = (1.f - zg) * ng;          // h_1[col], uniform across wave
        if (lane == 0)
            __hip_atomic_store(&dbuf[HDIM + col], h_prev,
                               __ATOMIC_RELAXED, __HIP_MEMORY_SCOPE_AGENT);
    }
    __syncthreads();   // drains vmcnt(0) per wave: payload ACKed at L3
    if (tid == 0)
        __hip_atomic_store(&flags[blk], 1, __ATOMIC_RELAXED, __HIP_MEMORY_SCOPE_AGENT);

    const int lbase = 33 * lane;          // P(32*lane + k) = 33*lane + k

    for (int t = 1; t < TSTEPS; ++t) {
        const int p = t & 1;

        // ---- discovery: poller tid<256 owns flag[tid]; fetch+stage payload ----
        if (tid < NBLK) {
            while (__hip_atomic_load(&flags[tid], __ATOMIC_RELAXED,
                                     __HIP_MEMORY_SCOPE_AGENT) < t) { }
            const ull* pay = (const ull*)(dbuf + p * HDIM) + 4 * tid;
            ull v0 = __hip_atomic_load(&pay[0], __ATOMIC_RELAXED, __HIP_MEMORY_SCOPE_AGENT);
            ull v1 = __hip_atomic_load(&pay[1], __ATOMIC_RELAXED, __HIP_MEMORY_SCOPE_AGENT);
            ull v2 = __hip_atomic_load(&pay[2], __ATOMIC_RELAXED, __HIP_MEMORY_SCOPE_AGENT);
            ull v3 = __hip_atomic_load(&pay[3], __ATOMIC_RELAXED, __HIP_MEMORY_SCOPE_AGENT);
            int b8 = 8 * tid;
            lds_h[p][P(b8 + 0)] = __uint_as_float((unsigned)v0);
            lds_h[p][P(b8 + 1)] = __uint_as_float((unsigned)(v0 >> 32));
            lds_h[p][P(b8 + 2)] = __uint_as_float((unsigned)v1);
            lds_h[p][P(b8 + 3)] = __uint_as_float((unsigned)(v1 >> 32));
            lds_h[p][P(b8 + 4)] = __uint_as_float((unsigned)v2);
            lds_h[p][P(b8 + 5)] = __uint_as_float((unsigned)(v2 >> 32));
            lds_h[p][P(b8 + 6)] = __uint_as_float((unsigned)v3);
            lds_h[p][P(b8 + 7)] = __uint_as_float((unsigned)(v3 >> 32));
        }
        __syncthreads();                   // B1: h_t staged

        // ---- 96 register-resident FMAs over this lane's 32 rows ----
        float a0 = 0.f, a1 = 0.f, a2 = 0.f;
        const float* hb = &lds_h[p][lbase];
#pragma unroll
        for (int k = 0; k < 32; ++k) {
            float hv = hb[k];
            a0 = fmaf(hv, wr[k], a0);
            a1 = fmaf(hv, wz[k], a1);
            a2 = fmaf(hv, wn[k], a2);
        }
        // ---- full intra-wave reduction: column sums in every lane ----
#pragma unroll
        for (int m = 1; m < 64; m <<= 1) {
            a0 += __shfl_xor(a0, m, 64);
            a1 += __shfl_xor(a1, m, 64);
            a2 += __shfl_xor(a2, m, 64);
        }

        // ---- finalize (uniform across wave) ----
        float xt = xs_l[t];
        float ar = fmaf(xt, vrc, crc) + a0;
        float az = fmaf(xt, vzc, czc) + a1;
        float an = fmaf(xt, vnc, cnc);
        float rg = sigmoid_f(ar), zg = sigmoid_f(az);
        float ng = tanh_f(an + rg * (a2 + bhc));
        float hnew = (1.f - zg) * ng + zg * h_prev;
        h_prev = hnew;

        if (t == TSTEPS - 1) {
            if (lane == 0) out[col] = hnew;
        } else {
            if (lane == 0)
                __hip_atomic_store(&dbuf[((t + 1) & 1) * HDIM + col], hnew,
                                   __ATOMIC_RELAXED, __HIP_MEMORY_SCOPE_AGENT);
            __syncthreads();               // B2: drains vmcnt => payload ACKed
            if (tid == 0)
                __hip_atomic_store(&flags[blk], t + 1,
                                   __ATOMIC_RELAXED, __HIP_MEMORY_SCOPE_AGENT);
        }
    }
}

extern "C" void kernel_launch(void* const* d_in, const int* in_sizes, int n_in,
                              void* d_out, int out_size, void* d_ws, size_t ws_size,
                              hipStream_t stream) {
    const float* x    = (const float*)d_in[0];
    const float* We   = (const float*)d_in[1];
    const float* be   = (const float*)d_in[2];
    const float* Wir  = (const float*)d_in[3];
    const float* bir  = (const float*)d_in[4];
    const float* Wiz  = (const float*)d_in[5];
    const float* biz  = (const float*)d_in[6];
    const float* Win  = (const float*)d_in[7];
    const float* bin_ = (const float*)d_in[8];
    const float* Whr  = (const float*)d_in[9];
    const float* Whz  = (const float*)d_in[10];
    const float* Whn  = (const float*)d_in[11];
    const float* bhn  = (const float*)d_in[12];

    int*   flags = (int*)d_ws;             // 256 ints; 0xAA poison = negative
    float* dbuf  = (float*)d_ws + 256;     // 2 x 2048 f32 payload (offset 1KB, 8B-aligned)

    gru_all<<<NBLK, NTHR, 0, stream>>>(x, We, be, Wir, bir, Wiz, biz, Win, bin_,
                                       Whr, Whz, Whn, bhn,
                                       (float*)d_out, flags, dbuf);
}

// Round 8
// 2553.146 us; speedup vs baseline: 1.7796x; 1.7796x over previous
//
#include <hip/hip_runtime.h>

#define HDIM 2048
#define TSTEPS 1024
#define NBLK 256
#define NTHR 512
#define CPB 8      // columns per block
#define TAGM 0x3FFu

typedef unsigned long long ull;

__device__ __forceinline__ int snake_src(int t) {
    int y = t >> 5, p = t & 31;
    return (y & 1) ? (y * 32 + 31 - p) : t;
}
__device__ __forceinline__ float sigmoid_f(float v) {
    return __builtin_amdgcn_rcpf(1.f + __expf(-v));
}
__device__ __forceinline__ float tanh_f(float v) {
    return 1.f - 2.f * __builtin_amdgcn_rcpf(__expf(2.f * v) + 1.f);
}

// ---------------------------------------------------------------------------
// Structure = the proven 2678us kernel (R2 design), ONLY the slot format
// changed: 4B f32 with 10-bit step tag in the low mantissa bits (was 8B
// {tag32,f32}). Parity double buffer keeps the ==tag check overwrite-safe.
// Polled footprint/block/round: 8KB = 128 lines (was 256); publish = one
// 32B coalesced wave store (8 lanes x 4B); tag error <= 2^-13 rel per hop.
// Poison 0xAA...: low10 = 682, but slots are rewritten every step and step
// 682's buffer has been overwritten 340 times by then — no false match.
// Max published tag = 1023 (t=1022 publishes h_1023); t=1023 writes out.
// ---------------------------------------------------------------------------
__global__ __launch_bounds__(NTHR, 2) void gru_all(
    const float* __restrict__ x,
    const float* __restrict__ We,  const float* __restrict__ be,
    const float* __restrict__ Wir, const float* __restrict__ bir,
    const float* __restrict__ Wiz, const float* __restrict__ biz,
    const float* __restrict__ Win, const float* __restrict__ bin_,
    const float* __restrict__ Whr, const float* __restrict__ Whz,
    const float* __restrict__ Whn, const float* __restrict__ bhn,
    float* __restrict__ out, unsigned* __restrict__ u0, unsigned* __restrict__ u1)
{
    const int tid  = threadIdx.x;
    const int blk  = blockIdx.x;
    const int c    = tid & 7;
    const int r    = tid >> 3;            // 0..63
    const int col  = blk * CPB + c;
    const int row0 = r * 32;
    const int lane = tid & 63, wv = tid >> 6;

    __shared__ __align__(16) float lds_h[2304];   // pad: i -> i + ((i>>6)<<2)
    __shared__ float sBe[HDIM];
    __shared__ float red[8][6][8];

    // ---- stage We/be (lds_h temporarily holds We) ----
    for (int i = tid; i < HDIM; i += NTHR) { lds_h[i] = We[i]; sBe[i] = be[i]; }
    __syncthreads();

    // ---- recurrent weights into registers (one-time) ----
    float wr[32], wz[32], wn[32];
#pragma unroll
    for (int k = 0; k < 32; ++k) {
        size_t off = (size_t)(row0 + k) * HDIM + col;
        wr[k] = Whr[off];
        wz[k] = Whz[off];
        wn[k] = Whn[off];
    }

    // ---- rank-1 input-path constants for this block's 8 columns ----
    float eR=0,eZ=0,eN=0,bRa=0,bZa=0,bNa=0;
#pragma unroll 8
    for (int k = 0; k < 32; ++k) {
        size_t off = (size_t)(row0 + k) * HDIM + col;
        float we = lds_h[row0 + k], bb = sBe[row0 + k];
        float w0 = Wir[off], w1 = Wiz[off], w2 = Win[off];
        eR  = fmaf(we, w0, eR);  bRa = fmaf(bb, w0, bRa);
        eZ  = fmaf(we, w1, eZ);  bZa = fmaf(bb, w1, bZa);
        eN  = fmaf(we, w2, eN);  bNa = fmaf(bb, w2, bNa);
    }
#pragma unroll
    for (int m = 8; m < 64; m <<= 1) {
        eR  += __shfl_xor(eR,  m, 64); eZ  += __shfl_xor(eZ,  m, 64);
        eN  += __shfl_xor(eN,  m, 64); bRa += __shfl_xor(bRa, m, 64);
        bZa += __shfl_xor(bZa, m, 64); bNa += __shfl_xor(bNa, m, 64);
    }
    if (lane < 8) {
        red[wv][0][lane]=eR;  red[wv][1][lane]=eZ;  red[wv][2][lane]=eN;
        red[wv][3][lane]=bRa; red[wv][4][lane]=bZa; red[wv][5][lane]=bNa;
    }
    __syncthreads();   // also fences lds_h(We)/sBe reads before lds_h reuse

    float vrc=0,vzc=0,vnc=0,crc=0,czc=0,cnc=0,bhc=0;
    if (tid < 8) {
#pragma unroll
        for (int w = 0; w < 8; ++w) {
            vrc += red[w][0][tid]; vzc += red[w][1][tid]; vnc += red[w][2][tid];
            crc += red[w][3][tid]; czc += red[w][4][tid]; cnc += red[w][5][tid];
        }
        crc += bir[col]; czc += biz[col]; cnc += bin_[col];
        bhc = bhn[col];

        // ---- step 0: h_0 == 0, fully local; publish h_1 with tag 1 ----
        float x0 = x[snake_src(0)];
        float ar = fmaf(x0, vrc, crc);
        float az = fmaf(x0, vzc, czc);
        float an = fmaf(x0, vnc, cnc);
        float rg = sigmoid_f(ar), zg = sigmoid_f(az);
        float ng = tanh_f(fmaf(rg, bhc, an));
        float h1 = (1.f - zg) * ng;
        unsigned pk = (__float_as_uint(h1) & ~TAGM) | 1u;
        __hip_atomic_store(&u1[col], pk, __ATOMIC_RELAXED, __HIP_MEMORY_SCOPE_AGENT);
    }

    const int sbase = tid * 4;                    // this thread's 4 h slots
    const int lwb   = sbase + ((sbase >> 6) << 2);  // padded LDS write base (16B aligned)
    const int lrb   = row0  + ((row0  >> 6) << 2);  // padded LDS read base
    const int pcol  = col + ((col >> 6) << 2);

    for (int t = 1; t < TSTEPS; ++t) {
        const unsigned* sin  = (t & 1) ? u1 : u0;
        unsigned*       sout = (t & 1) ? u0 : u1;
        const unsigned  tg   = (unsigned)t & TAGM;

        // ---- poll fused tag-in-mantissa slots: 2x8B loads = 4 values ----
        const ull* pp = (const ull*)sin + 2 * tid;
        ull v0, v1;
        for (;;) {
            v0 = __hip_atomic_load(&pp[0], __ATOMIC_RELAXED, __HIP_MEMORY_SCOPE_AGENT);
            v1 = __hip_atomic_load(&pp[1], __ATOMIC_RELAXED, __HIP_MEMORY_SCOPE_AGENT);
            unsigned a = (unsigned)v0, b = (unsigned)(v0 >> 32);
            unsigned d = (unsigned)v1, e = (unsigned)(v1 >> 32);
            if ((a & TAGM) == tg && (b & TAGM) == tg &&
                (d & TAGM) == tg && (e & TAGM) == tg) break;
        }
        float4 hq = make_float4(__uint_as_float((unsigned)v0        & ~TAGM),
                                __uint_as_float((unsigned)(v0 >> 32) & ~TAGM),
                                __uint_as_float((unsigned)v1        & ~TAGM),
                                __uint_as_float((unsigned)(v1 >> 32) & ~TAGM));
        *(float4*)&lds_h[lwb] = hq;
        __syncthreads();                          // BAR1: h_t staged

        // ---- 96 register-resident FMAs ----
        float a0 = 0.f, a1 = 0.f, a2 = 0.f;
#pragma unroll
        for (int k = 0; k < 32; ++k) {
            float hv = lds_h[lrb + k];
            a0 = fmaf(hv, wr[k], a0);
            a1 = fmaf(hv, wz[k], a1);
            a2 = fmaf(hv, wn[k], a2);
        }
#pragma unroll
        for (int m = 8; m < 64; m <<= 1) {
            a0 += __shfl_xor(a0, m, 64);
            a1 += __shfl_xor(a1, m, 64);
            a2 += __shfl_xor(a2, m, 64);
        }
        if (lane < 8) { red[wv][0][lane]=a0; red[wv][1][lane]=a1; red[wv][2][lane]=a2; }
        __syncthreads();                          // BAR2: partials ready

        // ---- finalize 8 columns, ONE 32B coalesced tagged publish ----
        if (tid < 8) {
            float Sr=0, Sz=0, Sn=0;
#pragma unroll
            for (int w = 0; w < 8; ++w) {
                Sr += red[w][0][tid]; Sz += red[w][1][tid]; Sn += red[w][2][tid];
            }
            float xt = x[snake_src(t)];
            float ar = fmaf(xt, vrc, crc) + Sr;
            float az = fmaf(xt, vzc, czc) + Sz;
            float an = fmaf(xt, vnc, cnc);
            float rg = sigmoid_f(ar), zg = sigmoid_f(az);
            float ng = tanh_f(an + rg * (Sn + bhc));
            float hold = lds_h[pcol];
            float hnew = (1.f - zg) * ng + zg * hold;
            if (t == TSTEPS - 1) {
                out[col] = hnew;
            } else {
                unsigned pk = (__float_as_uint(hnew) & ~TAGM) | ((unsigned)(t + 1) & TAGM);
                __hip_atomic_store(&sout[col], pk, __ATOMIC_RELAXED, __HIP_MEMORY_SCOPE_AGENT);
            }
        }
        __syncthreads();   // BAR3: protect lds_h/red before next staging
    }
}

extern "C" void kernel_launch(void* const* d_in, const int* in_sizes, int n_in,
                              void* d_out, int out_size, void* d_ws, size_t ws_size,
                              hipStream_t stream) {
    const float* x    = (const float*)d_in[0];
    const float* We   = (const float*)d_in[1];
    const float* be   = (const float*)d_in[2];
    const float* Wir  = (const float*)d_in[3];
    const float* bir  = (const float*)d_in[4];
    const float* Wiz  = (const float*)d_in[5];
    const float* biz  = (const float*)d_in[6];
    const float* Win  = (const float*)d_in[7];
    const float* bin_ = (const float*)d_in[8];
    const float* Whr  = (const float*)d_in[9];
    const float* Whz  = (const float*)d_in[10];
    const float* Whn  = (const float*)d_in[11];
    const float* bhn  = (const float*)d_in[12];

    unsigned* u0 = (unsigned*)d_ws;        // even-parity slots (2048 x 4B)
    unsigned* u1 = u0 + HDIM;              // odd-parity slots (8KB offset, 8B aligned)

    gru_all<<<NBLK, NTHR, 0, stream>>>(x, We, be, Wir, bir, Wiz, biz, Win, bin_,
                                       Whr, Whz, Whn, bhn,
                                       (float*)d_out, u0, u1);
}